// Round 9
// baseline (44.959 us; speedup 1.0000x reference)
//
#include <hip/hip_runtime.h>
#include <stdint.h>

// DecoupledMoE via bf16 MFMA, R9: async global->LDS staging.
// R8 post-mortem: scalar 4B x-loads (256B/instr, 840k instrs) made the kernel
// load-issue/latency bound (all pipes <10%). Now: stage x tile (64k x 128px,
// 32KB) with global_load_lds width=16 (1KB/instr, 32 instrs/block, async,
// no VGPR), read B-frags from LDS (2-way bank alias = free), x read ONCE.

typedef __bf16 bf16x8 __attribute__((ext_vector_type(8)));
typedef float  f32x16 __attribute__((ext_vector_type(16)));

#define HW    3136
#define CIN   64
#define COUT  64
#define PXB   128    // pixels per block
#define NPXB  25     // ceil(3136/128); last block overlaps 64 px (same values)

__device__ __forceinline__ void g2lds16(const float* g, float* lds_base) {
    // HW semantics: LDS dest = wave-uniform base + lane*16; global src per-lane.
    __builtin_amdgcn_global_load_lds(
        (const __attribute__((address_space(1))) void*)g,
        (__attribute__((address_space(3))) void*)lds_base,
        16, 0, 0);
}

__global__ __launch_bounds__(256, 4) void moe_mfma(
    const float* __restrict__ x,
    const float* __restrict__ weights,
    const int*   __restrict__ indices,
    const float* __restrict__ W_shared,
    const float* __restrict__ b_shared,
    const float* __restrict__ W_routed,
    const float* __restrict__ b_routed,
    float* __restrict__ out)
{
    __shared__ float xl[CIN * PXB];   // 32 KB, row-major [k][px]

    const int bs = blockIdx.y;
    int px0 = blockIdx.x * PXB;
    if (px0 > HW - PXB) px0 = HW - PXB;   // overlap: rewrites identical values

    const int wave = threadIdx.x >> 6;
    const int lane = threadIdx.x & 63;
    const int l5   = lane >> 5;
    const int l31  = lane & 31;

    const float wb = weights[bs];
    const int   e  = indices[bs];

    const float* __restrict__ xs = x + (size_t)bs * CIN * HW;

    // ---- async stage: wave w covers k-rows [16w, 16w+16), 8 x 1KB instrs ----
    // instr i: LDS floats [(16w+2i)*128, +256) = rows 16w+2i..+1; lane l writes
    // floats 4l..4l+3 -> row_local = l>>5, px = 4*(l&31); global src matches.
    #pragma unroll
    for (int i = 0; i < 8; ++i) {
        const int row = 16 * wave + 2 * i;
        g2lds16(xs + (size_t)(row + l5) * HW + px0 + 4 * l31,
                xl + row * PXB);
    }

    // ---- A fragments + fused bias while stages are in flight ----
    const int ob = (wave >> 1) * 32;     // this wave's o-tile (0 or 32)
    bf16x8 afrag[4];
    {
        const float* Ws = W_shared + (size_t)(ob + l31) * CIN + 8 * l5;
        const float* Wr = W_routed + ((size_t)e * COUT + ob + l31) * CIN + 8 * l5;
        #pragma unroll
        for (int ks = 0; ks < 4; ++ks) {
            float4 s0 = *(const float4*)(Ws + 16 * ks);
            float4 s1 = *(const float4*)(Ws + 16 * ks + 4);
            float4 r0 = *(const float4*)(Wr + 16 * ks);
            float4 r1 = *(const float4*)(Wr + 16 * ks + 4);
            afrag[ks][0] = (__bf16)(s0.x + wb * r0.x);
            afrag[ks][1] = (__bf16)(s0.y + wb * r0.y);
            afrag[ks][2] = (__bf16)(s0.z + wb * r0.z);
            afrag[ks][3] = (__bf16)(s0.w + wb * r0.w);
            afrag[ks][4] = (__bf16)(s1.x + wb * r1.x);
            afrag[ks][5] = (__bf16)(s1.y + wb * r1.y);
            afrag[ks][6] = (__bf16)(s1.z + wb * r1.z);
            afrag[ks][7] = (__bf16)(s1.w + wb * r1.w);
        }
    }
    f32x16 biasv;
    #pragma unroll
    for (int g = 0; g < 4; ++g) {
        const int o4 = ob + 8 * g + 4 * l5;
        float4 s = *(const float4*)(b_shared + o4);
        float4 r = *(const float4*)(b_routed + e * COUT + o4);
        biasv[4 * g + 0] = s.x + wb * r.x;
        biasv[4 * g + 1] = s.y + wb * r.y;
        biasv[4 * g + 2] = s.z + wb * r.z;
        biasv[4 * g + 3] = s.w + wb * r.w;
    }

    __syncthreads();   // compiler drains vmcnt(0) before s_barrier -> LDS valid

    // ---- compute: wave = o-tile (w>>1) x px-half (w&1); 2 tiles of 32 px ----
    const int pxh = (wave & 1) * 64;
    float* __restrict__ os = out + (size_t)bs * COUT * HW + px0;

    #pragma unroll
    for (int t = 0; t < 2; ++t) {
        const int pxl = pxh + 32 * t + l31;
        f32x16 acc = biasv;
        #pragma unroll
        for (int ks = 0; ks < 4; ++ks) {
            // B frag: x[16ks + 8*l5 + j][pxl]; lanes 0-31 consecutive floats
            // -> conflict-free (l5 half offset 4096B = same banks, 2-way free)
            bf16x8 bfr;
            #pragma unroll
            for (int j = 0; j < 8; ++j)
                bfr[j] = (__bf16)xl[(16 * ks + 8 * l5 + j) * PXB + pxl];
            acc = __builtin_amdgcn_mfma_f32_32x32x16_bf16(afrag[ks], bfr, acc, 0, 0, 0);
        }
        // C store: verified layout col=l31, row=(r&3)+8*(r>>2)+4*l5
        #pragma unroll
        for (int r = 0; r < 16; ++r) {
            const int row = ob + (r & 3) + 8 * (r >> 2) + 4 * l5;
            os[(size_t)row * HW + pxl] = acc[r];
        }
    }
}

extern "C" void kernel_launch(void* const* d_in, const int* in_sizes, int n_in,
                              void* d_out, int out_size, void* d_ws, size_t ws_size,
                              hipStream_t stream) {
    const float* x        = (const float*)d_in[0];
    const float* weights  = (const float*)d_in[1];
    const int*   indices  = (const int*)  d_in[2];
    const float* W_shared = (const float*)d_in[3];
    const float* b_shared = (const float*)d_in[4];
    const float* W_routed = (const float*)d_in[5];
    const float* b_routed = (const float*)d_in[6];
    float* out = (float*)d_out;

    // 25 px-chunks x 128 samples; block = all 64 out-ch x 128 px
    moe_mfma<<<dim3(NPXB, 128), 256, 0, stream>>>(
        x, weights, indices, W_shared, b_shared, W_routed, b_routed, out);
}

// Round 10
// 37.577 us; speedup vs baseline: 1.1964x; 1.1964x over previous
//
#include <hip/hip_runtime.h>
#include <stdint.h>

// DecoupledMoE via bf16 MFMA, R10.
// R8/R9 identical 44.95us despite different load paths -> request-count x
// latency wall. Biggest request source: per-wave strided W loads (2048
// lines/block). R10: (1) coop coalesced W_eff build into swizzled bf16 LDS,
// ds_read_b128 A-frags; (2) 7-tile blocks, double-buffered x staging
// (global_load_lds w16), stage(t+1) overlaps compute(t); (3) exact 7x448 px.

typedef __bf16 bf16x8 __attribute__((ext_vector_type(8)));
typedef float  f32x16 __attribute__((ext_vector_type(16)));

#define HW    3136
#define CIN   64
#define COUT  64
#define PXB   64               // pixels per tile
#define NT    7                // tiles per block
#define BPX   (PXB * NT)       // 448 px per block; 7 blocks cover 3136 exactly

__device__ __forceinline__ void g2lds16(const float* g, float* lds_base) {
    // LDS dest = wave-uniform base + lane*16; global src per-lane.
    __builtin_amdgcn_global_load_lds(
        (const __attribute__((address_space(1))) void*)g,
        (__attribute__((address_space(3))) void*)lds_base,
        16, 0, 0);
}

__global__ __launch_bounds__(256, 4) void moe_mfma(
    const float* __restrict__ x,
    const float* __restrict__ weights,
    const int*   __restrict__ indices,
    const float* __restrict__ W_shared,
    const float* __restrict__ b_shared,
    const float* __restrict__ W_routed,
    const float* __restrict__ b_routed,
    float* __restrict__ out)
{
    __shared__ __attribute__((aligned(16))) float  xl[2][CIN * PXB]; // 2x16KB
    __shared__ __attribute__((aligned(16))) __bf16 wl[COUT * CIN];   // 8KB swizzled

    const int bs      = blockIdx.y;
    const int px_base = blockIdx.x * BPX;

    const int tid  = threadIdx.x;
    const int wave = tid >> 6;
    const int lane = tid & 63;
    const int l5   = lane >> 5;
    const int l31  = lane & 31;

    const float wb = weights[bs];
    const int   e  = indices[bs];

    const float* __restrict__ xs = x   + (size_t)bs * CIN  * HW;
    float*       __restrict__ os = out + (size_t)bs * COUT * HW;

    // ---- coop W_eff: coalesced fp32 loads -> bf16 swizzled LDS (512 lines) ----
    {
        const float4* Ws4 = (const float4*)W_shared;
        const float4* Wr4 = (const float4*)(W_routed + (size_t)e * (COUT * CIN));
        #pragma unroll
        for (int it = 0; it < 4; ++it) {
            const int f4 = tid + it * 256;       // float4 index 0..1023
            float4 s = Ws4[f4], r = Wr4[f4];
            const int o = f4 >> 4;               // out-ch row (16 float4/row)
            const int k = (f4 & 15) * 4;         // col
            // byte addr = (o*64+k)*2 XOR-swizzled by row (T2): 8B group intact
            __bf16* dst = (__bf16*)((char*)wl +
                          ((((o * 64 + k) * 2)) ^ ((o & 7) << 4)));
            dst[0] = (__bf16)(s.x + wb * r.x);
            dst[1] = (__bf16)(s.y + wb * r.y);
            dst[2] = (__bf16)(s.z + wb * r.z);
            dst[3] = (__bf16)(s.w + wb * r.w);
        }
    }

    // ---- stage tile 0 (async, 16 x 1KB per block) ----
    // wave w stages k-rows [16w,16w+16): instr i covers 4 rows x 64 px
    #define STAGE(BI, T) do {                                              \
        const float* xs_t = xs + px_base + (T) * PXB;                      \
        _Pragma("unroll")                                                  \
        for (int i_ = 0; i_ < 4; ++i_) {                                   \
            const int row_ = 16 * wave + 4 * i_;                           \
            g2lds16(xs_t + (size_t)(row_ + (lane >> 4)) * HW + 4 * (lane & 15), \
                    &xl[BI][row_ * PXB]);                                  \
        }                                                                  \
    } while (0)

    STAGE(0, 0);

    // ---- fused bias while loads are in flight ----
    const int ob = (wave >> 1) * 32;    // this wave's o-tile (0 or 32)
    f32x16 biasv;
    #pragma unroll
    for (int g = 0; g < 4; ++g) {
        const int o4 = ob + 8 * g + 4 * l5;
        float4 s = *(const float4*)(b_shared + o4);
        float4 r = *(const float4*)(b_routed + e * COUT + o4);
        biasv[4 * g + 0] = s.x + wb * r.x;
        biasv[4 * g + 1] = s.y + wb * r.y;
        biasv[4 * g + 2] = s.z + wb * r.z;
        biasv[4 * g + 3] = s.w + wb * r.w;
    }

    __syncthreads();   // drains W_eff writes + stage0 (vmcnt/lgkm before barrier)

    // ---- A fragments from swizzled LDS: 4 x ds_read_b128 (4-way, once) ----
    bf16x8 afrag[4];
    {
        const int arow = ob + l31;
        #pragma unroll
        for (int ks = 0; ks < 4; ++ks) {
            const int byte = ((arow * 64 + 16 * ks + 8 * l5) * 2)
                             ^ ((arow & 7) << 4);
            afrag[ks] = *(const bf16x8*)((const char*)wl + byte);
        }
    }

    // ---- main loop: stage(t+1) overlaps compute(t); 1 barrier/tile ----
    const int pxl = (wave & 1) * 32 + l31;   // wave = o-tile x px-half

    #pragma unroll 1
    for (int t = 0; t < NT; ++t) {
        if (t + 1 < NT) STAGE((t + 1) & 1, t + 1);

        const float* xb = xl[t & 1];
        f32x16 acc = biasv;
        #pragma unroll
        for (int ks = 0; ks < 4; ++ks) {
            // lanes 0-31 consecutive floats -> conflict-free (2-way free)
            bf16x8 bfr;
            #pragma unroll
            for (int j = 0; j < 8; ++j)
                bfr[j] = (__bf16)xb[(16 * ks + 8 * l5 + j) * PXB + pxl];
            acc = __builtin_amdgcn_mfma_f32_32x32x16_bf16(afrag[ks], bfr, acc, 0, 0, 0);
        }

        // C store: verified layout col=l31, row=(r&3)+8*(r>>2)+4*l5
        float* os_t = os + px_base + t * PXB;
        #pragma unroll
        for (int r = 0; r < 16; ++r) {
            const int row = ob + (r & 3) + 8 * (r >> 2) + 4 * l5;
            os_t[(size_t)row * HW + pxl] = acc[r];
        }

        __syncthreads();   // stage(t+1) complete; buf[t&1] free for t+2
    }
}

extern "C" void kernel_launch(void* const* d_in, const int* in_sizes, int n_in,
                              void* d_out, int out_size, void* d_ws, size_t ws_size,
                              hipStream_t stream) {
    const float* x        = (const float*)d_in[0];
    const float* weights  = (const float*)d_in[1];
    const int*   indices  = (const int*)  d_in[2];
    const float* W_shared = (const float*)d_in[3];
    const float* b_shared = (const float*)d_in[4];
    const float* W_routed = (const float*)d_in[5];
    const float* b_routed = (const float*)d_in[6];
    float* out = (float*)d_out;

    // 7 px-groups x 128 samples = 896 blocks, 4/CU LDS cap -> all resident
    moe_mfma<<<dim3(7, 128), 256, 0, stream>>>(
        x, weights, indices, W_shared, b_shared, W_routed, b_routed, out);
}

// Round 11
// 37.469 us; speedup vs baseline: 1.1999x; 1.0029x over previous
//
#include <hip/hip_runtime.h>
#include <stdint.h>

// DecoupledMoE via bf16 MFMA, R11.
// R10 = 37.6us, HBM 4.0 TB/s (~80% of mixed ceiling). Residual: per-tile
// __syncthreads forces vmcnt(0) -> drains 16 fresh global stores every tile
// (store-ack ~300-600cy x 7 tiles x 3.5 rounds). R11: T4 counted-vmcnt
// barrier -- per tile {ds_read(t); STAGE(t+1); MFMA; stores;
// s_waitcnt vmcnt(16); s_barrier}: stage retired (4 oldest), stores stay
// in flight across the barrier. Last tile: no barrier.

typedef __bf16 bf16x8 __attribute__((ext_vector_type(8)));
typedef float  f32x16 __attribute__((ext_vector_type(16)));

#define HW    3136
#define CIN   64
#define COUT  64
#define PXB   64               // pixels per tile
#define NT    7                // tiles per block
#define BPX   (PXB * NT)       // 448 px per block; 7 blocks cover 3136 exactly

__device__ __forceinline__ void g2lds16(const float* g, float* lds_base) {
    // LDS dest = wave-uniform base + lane*16; global src per-lane.
    __builtin_amdgcn_global_load_lds(
        (const __attribute__((address_space(1))) void*)g,
        (__attribute__((address_space(3))) void*)lds_base,
        16, 0, 0);
}

__global__ __launch_bounds__(256, 4) void moe_mfma(
    const float* __restrict__ x,
    const float* __restrict__ weights,
    const int*   __restrict__ indices,
    const float* __restrict__ W_shared,
    const float* __restrict__ b_shared,
    const float* __restrict__ W_routed,
    const float* __restrict__ b_routed,
    float* __restrict__ out)
{
    __shared__ __attribute__((aligned(16))) float  xl[2][CIN * PXB]; // 2x16KB
    __shared__ __attribute__((aligned(16))) __bf16 wl[COUT * CIN];   // 8KB swizzled

    const int bs      = blockIdx.y;
    const int px_base = blockIdx.x * BPX;

    const int tid  = threadIdx.x;
    const int wave = tid >> 6;
    const int lane = tid & 63;
    const int l5   = lane >> 5;
    const int l31  = lane & 31;

    const float wb = weights[bs];
    const int   e  = indices[bs];

    const float* __restrict__ xs = x   + (size_t)bs * CIN  * HW;
    float*       __restrict__ os = out + (size_t)bs * COUT * HW;

    // ---- coop W_eff: coalesced fp32 loads -> bf16 swizzled LDS ----
    {
        const float4* Ws4 = (const float4*)W_shared;
        const float4* Wr4 = (const float4*)(W_routed + (size_t)e * (COUT * CIN));
        #pragma unroll
        for (int it = 0; it < 4; ++it) {
            const int f4 = tid + it * 256;       // float4 index 0..1023
            float4 s = Ws4[f4], r = Wr4[f4];
            const int o = f4 >> 4;               // out-ch row (16 float4/row)
            const int k = (f4 & 15) * 4;         // col
            __bf16* dst = (__bf16*)((char*)wl +
                          ((((o * 64 + k) * 2)) ^ ((o & 7) << 4)));
            dst[0] = (__bf16)(s.x + wb * r.x);
            dst[1] = (__bf16)(s.y + wb * r.y);
            dst[2] = (__bf16)(s.z + wb * r.z);
            dst[3] = (__bf16)(s.w + wb * r.w);
        }
    }

    // ---- stage macro: wave w covers k-rows [16w,16w+16), 4 x 1KB instrs ----
    #define STAGE(BI, T) do {                                              \
        const float* xs_t = xs + px_base + (T) * PXB;                      \
        _Pragma("unroll")                                                  \
        for (int i_ = 0; i_ < 4; ++i_) {                                   \
            const int row_ = 16 * wave + 4 * i_;                           \
            g2lds16(xs_t + (size_t)(row_ + (lane >> 4)) * HW + 4 * (lane & 15), \
                    &xl[BI][row_ * PXB]);                                  \
        }                                                                  \
    } while (0)

    STAGE(0, 0);

    // ---- fused bias while loads are in flight ----
    const int ob = (wave >> 1) * 32;    // this wave's o-tile (0 or 32)
    f32x16 biasv;
    #pragma unroll
    for (int g = 0; g < 4; ++g) {
        const int o4 = ob + 8 * g + 4 * l5;
        float4 s = *(const float4*)(b_shared + o4);
        float4 r = *(const float4*)(b_routed + e * COUT + o4);
        biasv[4 * g + 0] = s.x + wb * r.x;
        biasv[4 * g + 1] = s.y + wb * r.y;
        biasv[4 * g + 2] = s.z + wb * r.z;
        biasv[4 * g + 3] = s.w + wb * r.w;
    }

    __syncthreads();   // full drain once: W_eff ds_writes + stage0

    // ---- A fragments from swizzled LDS: 4 x ds_read_b128 (once) ----
    bf16x8 afrag[4];
    {
        const int arow = ob + l31;
        #pragma unroll
        for (int ks = 0; ks < 4; ++ks) {
            const int byte = ((arow * 64 + 16 * ks + 8 * l5) * 2)
                             ^ ((arow & 7) << 4);
            afrag[ks] = *(const bf16x8*)((const char*)wl + byte);
        }
    }

    const int pxl = (wave & 1) * 32 + l31;   // wave = o-tile x px-half

    #pragma unroll 1
    for (int t = 0; t < NT; ++t) {
        const float* xb = xl[t & 1];

        // (1) ds_reads FIRST (before STAGE: no gload_lds/ds_read alias stall)
        float xf[4][8];
        #pragma unroll
        for (int ks = 0; ks < 4; ++ks)
            #pragma unroll
            for (int j = 0; j < 8; ++j)
                xf[ks][j] = xb[(16 * ks + 8 * l5 + j) * PXB + pxl];

        // (2) issue next tile's stage (4 gload_lds per wave, stays in flight)
        if (t + 1 < NT) STAGE((t + 1) & 1, t + 1);

        // (3) convert + MFMA
        f32x16 acc = biasv;
        #pragma unroll
        for (int ks = 0; ks < 4; ++ks) {
            bf16x8 bfr;
            #pragma unroll
            for (int j = 0; j < 8; ++j) bfr[j] = (__bf16)xf[ks][j];
            acc = __builtin_amdgcn_mfma_f32_32x32x16_bf16(afrag[ks], bfr, acc, 0, 0, 0);
        }

        // (4) stores (left in flight across the barrier)
        float* os_t = os + px_base + t * PXB;
        #pragma unroll
        for (int r = 0; r < 16; ++r) {
            const int row = ob + (r & 3) + 8 * (r >> 2) + 4 * l5;
            os_t[(size_t)row * HW + pxl] = acc[r];
        }

        // (5) counted wait: retire the 4 stage ops only (16 stores newest,
        //     allowed to remain outstanding) -> barrier
        if (t + 1 < NT) {
            asm volatile("s_waitcnt vmcnt(16)" ::: "memory");
            __builtin_amdgcn_s_barrier();
            __builtin_amdgcn_sched_barrier(0);
        }
    }
}

extern "C" void kernel_launch(void* const* d_in, const int* in_sizes, int n_in,
                              void* d_out, int out_size, void* d_ws, size_t ws_size,
                              hipStream_t stream) {
    const float* x        = (const float*)d_in[0];
    const float* weights  = (const float*)d_in[1];
    const int*   indices  = (const int*)  d_in[2];
    const float* W_shared = (const float*)d_in[3];
    const float* b_shared = (const float*)d_in[4];
    const float* W_routed = (const float*)d_in[5];
    const float* b_routed = (const float*)d_in[6];
    float* out = (float*)d_out;

    // 7 px-groups x 128 samples = 896 blocks
    moe_mfma<<<dim3(7, 128), 256, 0, stream>>>(
        x, weights, indices, W_shared, b_shared, W_routed, b_routed, out);
}